// Round 1
// baseline (2650.663 us; speedup 1.0000x reference)
//
#include <hip/hip_runtime.h>
#include <hip/hip_bf16.h>
#include <math.h>

#define B_CONST 256
#define T_CONST 8192
#define F_CONST 2
#define P_CONST 16
#define H_CONST 1024

// ---------------- kernel 1: per-batch valid count (sum of mask) ----------------
__global__ void k_valid(const float* __restrict__ x, int* __restrict__ valid) {
    int b = blockIdx.x;
    const float* row = x + (size_t)b * (T_CONST * F_CONST);
    float s = 0.f;
    for (int t = threadIdx.x; t < T_CONST; t += blockDim.x)
        s += row[2 * t + 1];
    __shared__ float red[256];
    red[threadIdx.x] = s;
    __syncthreads();
    for (int off = 128; off > 0; off >>= 1) {
        if (threadIdx.x < off) red[threadIdx.x] += red[threadIdx.x + off];
        __syncthreads();
    }
    if (threadIdx.x == 0) valid[b] = (int)(red[0] + 0.5f);
}

// ---------------- kernel 2: pc + scan; also writes pc (as float) to out tail ----
__global__ void k_scan(const int* __restrict__ valid, int* __restrict__ pc,
                       int* __restrict__ starts, int* __restrict__ cum,
                       float* __restrict__ out_pc) {
    __shared__ int s[B_CONST];
    int t = threadIdx.x;
    int v = valid[t];
    int p = (v + P_CONST - 1) / P_CONST;
    s[t] = p;
    __syncthreads();
    for (int off = 1; off < B_CONST; off <<= 1) {
        int add = (t >= off) ? s[t - off] : 0;
        __syncthreads();
        s[t] += add;
        __syncthreads();
    }
    pc[t] = p;
    cum[t] = s[t];
    starts[t] = s[t] - p;
    out_pc[t] = (float)p;
}

// ---------------- kernel 3: gather patches (total x 16, fp32) ------------------
__global__ void k_gather(const float* __restrict__ x, const int* __restrict__ valid,
                         const int* __restrict__ cum, const int* __restrict__ starts,
                         float* __restrict__ patches, int total) {
    int tid = blockIdx.x * blockDim.x + threadIdx.x;
    if (tid >= total * P_CONST) return;
    int j = tid / P_CONST, k = tid % P_CONST;
    // smallest b with cum[b] > j
    int lo = 0, hi = B_CONST - 1;
    while (lo < hi) { int mid = (lo + hi) >> 1; if (cum[mid] > j) hi = mid; else lo = mid + 1; }
    int b = lo;
    int p = j - starts[b];
    int idx = p * P_CONST + k;
    float v = 0.f;
    if (idx < valid[b]) v = x[(size_t)b * (T_CONST * F_CONST) + 2 * idx];
    patches[tid] = v;
}

// ---------------- tiled GEMM: C = act(A @ Bw + bias) ---------------------------
// A: MxK row-major (TA = float or bf16), Bw: KxN row-major fp32, C: MxN (TOut)
// 64x64 tile per 256-thread block, 4x4 per thread, BK=16, fp32 accumulate.
template <typename TA, bool GELU, typename TOut>
__global__ void k_gemm(const TA* __restrict__ A, const float* __restrict__ Bw,
                       const float* __restrict__ bias, TOut* __restrict__ C,
                       int M, int N, int K) {
    __shared__ float As[16][65];  // [k][m], +1 pad to break bank conflicts
    __shared__ float Bs[16][65];  // [k][n]
    const int tx = threadIdx.x % 16;
    const int ty = threadIdx.x / 16;
    const int brow = blockIdx.y * 64;
    const int bcol = blockIdx.x * 64;
    float acc[4][4] = {};

    const int e = threadIdx.x * 4;
    const int ar = e / 16, ac = e % 16;   // A-tile: row 0..63, k 0..15 (4 consecutive k)
    const int bkr = e / 64, bnc = e % 64; // B-tile: k 0..15, n 0..63 (4 consecutive n)

    for (int kt = 0; kt < K; kt += 16) {
        int gr = brow + ar; if (gr >= M) gr = M - 1;
        const TA* ap = A + (size_t)gr * K + kt + ac;
#pragma unroll
        for (int i = 0; i < 4; ++i) As[ac + i][ar] = (float)ap[i];
        const float* bp = Bw + (size_t)(kt + bkr) * N + bcol + bnc;
#pragma unroll
        for (int i = 0; i < 4; ++i) Bs[bkr][bnc + i] = bp[i];
        __syncthreads();
#pragma unroll
        for (int k = 0; k < 16; ++k) {
            float a[4], bb[4];
#pragma unroll
            for (int i = 0; i < 4; ++i) a[i] = As[k][ty * 4 + i];
#pragma unroll
            for (int j = 0; j < 4; ++j) bb[j] = Bs[k][tx * 4 + j];
#pragma unroll
            for (int i = 0; i < 4; ++i)
#pragma unroll
                for (int j = 0; j < 4; ++j)
                    acc[i][j] += a[i] * bb[j];
        }
        __syncthreads();
    }

#pragma unroll
    for (int i = 0; i < 4; ++i) {
        int row = brow + ty * 4 + i;
        if (row >= M) continue;
#pragma unroll
        for (int j = 0; j < 4; ++j) {
            int col = bcol + tx * 4 + j;
            float v = acc[i][j] + bias[col];
            if (GELU) v = 0.5f * v * (1.f + erff(v * 0.70710678118654752f));
            C[(size_t)row * N + col] = (TOut)v;
        }
    }
}

extern "C" void kernel_launch(void* const* d_in, const int* in_sizes, int n_in,
                              void* d_out, int out_size, void* d_ws, size_t ws_size,
                              hipStream_t stream) {
    const float* x  = (const float*)d_in[0];
    const float* w1 = (const float*)d_in[1];
    const float* b1 = (const float*)d_in[2];
    const float* w2 = (const float*)d_in[3];
    const float* b2 = (const float*)d_in[4];
    const float* w3 = (const float*)d_in[5];
    const float* b3 = (const float*)d_in[6];

    const int total = (out_size - B_CONST) / H_CONST;  // 32896
    float* out = (float*)d_out;
    float* out_pc = out + (size_t)total * H_CONST;

    char* ws = (char*)d_ws;
    int* valid  = (int*)ws;       // 256 ints
    int* pc     = valid + 256;
    int* starts = pc + 256;
    int* cum    = starts + 256;
    float* patches = (float*)(ws + 4096);
    size_t patches_bytes = ((size_t)total * P_CONST * sizeof(float) + 255) & ~(size_t)255;
    __hip_bfloat16* h1 = (__hip_bfloat16*)(ws + 4096 + patches_bytes);
    __hip_bfloat16* h2 = h1 + (size_t)total * H_CONST;

    k_valid<<<B_CONST, 256, 0, stream>>>(x, valid);
    k_scan<<<1, B_CONST, 0, stream>>>(valid, pc, starts, cum, out_pc);
    int nel = total * P_CONST;
    k_gather<<<(nel + 255) / 256, 256, 0, stream>>>(x, valid, cum, starts, patches, total);

    dim3 blk(256);
    dim3 g((H_CONST) / 64, (total + 63) / 64);
    k_gemm<float, true, __hip_bfloat16><<<g, blk, 0, stream>>>(patches, w1, b1, h1, total, H_CONST, P_CONST);
    k_gemm<__hip_bfloat16, true, __hip_bfloat16><<<g, blk, 0, stream>>>(h1, w2, b2, h2, total, H_CONST, H_CONST);
    k_gemm<__hip_bfloat16, false, float><<<g, blk, 0, stream>>>(h2, w3, b3, out, total, H_CONST, H_CONST);
}

// Round 2
// 330.358 us; speedup vs baseline: 8.0236x; 8.0236x over previous
//
#include <hip/hip_runtime.h>
#include <hip/hip_bf16.h>
#include <math.h>

#define B_CONST 256
#define T_CONST 8192
#define P_CONST 16
#define H_CONST 1024

typedef __bf16 bf16x8 __attribute__((ext_vector_type(8)));
typedef float  f32x4  __attribute__((ext_vector_type(4)));

typedef __attribute__((address_space(3))) void       as3_void;
typedef const __attribute__((address_space(1))) void as1_cvoid;

__device__ __forceinline__ void gload_lds16(const void* g, void* l) {
    __builtin_amdgcn_global_load_lds((as1_cvoid*)g, (as3_void*)l, 16, 0, 0);
}

// ---------------- kernel 1: per-batch valid count (sum of mask) ----------------
__global__ void k_valid(const float* __restrict__ x, int* __restrict__ valid) {
    int b = blockIdx.x;
    const float* row = x + (size_t)b * (T_CONST * 2);
    float s = 0.f;
    for (int t = threadIdx.x; t < T_CONST; t += blockDim.x)
        s += row[2 * t + 1];
    __shared__ float red[256];
    red[threadIdx.x] = s;
    __syncthreads();
    for (int off = 128; off > 0; off >>= 1) {
        if (threadIdx.x < off) red[threadIdx.x] += red[threadIdx.x + off];
        __syncthreads();
    }
    if (threadIdx.x == 0) valid[b] = (int)(red[0] + 0.5f);
}

// ---------------- kernel 2: pc + scan; writes pc (as float) to out tail --------
__global__ void k_scan(const int* __restrict__ valid, int* __restrict__ pc,
                       int* __restrict__ starts, int* __restrict__ cum,
                       float* __restrict__ out_pc) {
    __shared__ int s[B_CONST];
    int t = threadIdx.x;
    int v = valid[t];
    int p = (v + P_CONST - 1) / P_CONST;
    s[t] = p;
    __syncthreads();
    for (int off = 1; off < B_CONST; off <<= 1) {
        int add = (t >= off) ? s[t - off] : 0;
        __syncthreads();
        s[t] += add;
        __syncthreads();
    }
    pc[t] = p;
    cum[t] = s[t];
    starts[t] = s[t] - p;
    out_pc[t] = (float)p;
}

// ---------------- kernel 3: gather patches (total x 32 bf16, K padded) ---------
__global__ void k_gather(const float* __restrict__ x, const int* __restrict__ valid,
                         const int* __restrict__ cum, const int* __restrict__ starts,
                         __bf16* __restrict__ patches, int total) {
    int tid = blockIdx.x * blockDim.x + threadIdx.x;
    if (tid >= total * 32) return;
    int j = tid >> 5, k = tid & 31;
    int lo = 0, hi = B_CONST - 1;
    while (lo < hi) { int mid = (lo + hi) >> 1; if (cum[mid] > j) hi = mid; else lo = mid + 1; }
    int b = lo;
    int p = j - starts[b];
    float v = 0.f;
    if (k < 16) {
        int idx = p * P_CONST + k;
        if (idx < valid[b]) v = x[(size_t)b * (T_CONST * 2) + 2 * idx];
    }
    patches[tid] = (__bf16)v;
}

// ---------------- weight prep: transpose K x N fp32 -> N x K bf16 --------------
__global__ void k_transpose_cvt(const float* __restrict__ W, __bf16* __restrict__ WT,
                                int Kdim, int Ndim) {
    __shared__ float tile[32][33];
    int n0 = blockIdx.x * 32, k0 = blockIdx.y * 32;
    int c = threadIdx.x & 31, r0 = threadIdx.x >> 5;
    for (int r = r0; r < 32; r += 8) tile[r][c] = W[(size_t)(k0 + r) * Ndim + n0 + c];
    __syncthreads();
    for (int r = r0; r < 32; r += 8) WT[(size_t)(n0 + r) * Kdim + k0 + c] = (__bf16)tile[c][r];
}

// w1 is 16 x 1024 -> w1t 1024 x 32 (zero-padded K)
__global__ void k_w1t(const float* __restrict__ w1, __bf16* __restrict__ w1t) {
    int n = blockIdx.x * 256 + threadIdx.x;
    if (n >= H_CONST) return;
    for (int k = 0; k < 32; ++k)
        w1t[n * 32 + k] = (k < 16) ? (__bf16)w1[k * H_CONST + n] : (__bf16)0.f;
}

// ---------------- MFMA GEMM: C = act(A @ WT^T + bias) --------------------------
// A: M x K bf16 row-major.  WT: N x K bf16 row-major (i.e. W transposed).
// 128x128 tile, 4 waves (2x2), BK=32, mfma_f32_16x16x32_bf16, m97 structure.
template <bool GELU, typename TOut>
__global__ __launch_bounds__(256) void k_mfma_gemm(
    const __bf16* __restrict__ A, const __bf16* __restrict__ WT,
    const float* __restrict__ bias, TOut* __restrict__ C,
    int M, int N, int K) {
    __shared__ __bf16 As[128][32];
    __shared__ __bf16 Bs[128][32];

    const int lane = threadIdx.x & 63;
    const int wid  = threadIdx.x >> 6;
    const int wr = wid >> 1, wc = wid & 1;
    const int brow = blockIdx.y * 128;
    const int bcol = blockIdx.x * 128;

    f32x4 acc[4][4];
#pragma unroll
    for (int i = 0; i < 4; ++i)
#pragma unroll
        for (int j = 0; j < 4; ++j)
            acc[i][j] = (f32x4){0.f, 0.f, 0.f, 0.f};

    // staging: each wave issues 2 A-loads + 2 B-loads of 16 rows each.
    const int sr = lane >> 2;         // row within 16-row chunk
    const int sc = (lane & 3) * 8;    // elem offset within 32-elem row
    const size_t a_base = (size_t)(brow + wid * 16 + sr) * K + sc;
    const size_t b_base = (size_t)(bcol + wid * 16 + sr) * K + sc;
    const size_t stride64 = (size_t)64 * K;

    const int lr = lane & 15;
    const int lk = (lane >> 4) * 8;

    for (int kt = 0; kt < K; kt += 32) {
        gload_lds16(A  + a_base + kt,            &As[wid * 16][0]);
        gload_lds16(A  + a_base + stride64 + kt, &As[64 + wid * 16][0]);
        gload_lds16(WT + b_base + kt,            &Bs[wid * 16][0]);
        gload_lds16(WT + b_base + stride64 + kt, &Bs[64 + wid * 16][0]);
        __syncthreads();

        bf16x8 af[4], bfr[4];
#pragma unroll
        for (int mf = 0; mf < 4; ++mf)
            af[mf] = *(const bf16x8*)&As[wr * 64 + mf * 16 + lr][lk];
#pragma unroll
        for (int nf = 0; nf < 4; ++nf)
            bfr[nf] = *(const bf16x8*)&Bs[wc * 64 + nf * 16 + lr][lk];
#pragma unroll
        for (int mf = 0; mf < 4; ++mf)
#pragma unroll
            for (int nf = 0; nf < 4; ++nf)
                acc[mf][nf] = __builtin_amdgcn_mfma_f32_16x16x32_bf16(
                    af[mf], bfr[nf], acc[mf][nf], 0, 0, 0);
        __syncthreads();
    }

    // epilogue: C row = (lane>>4)*4 + reg, col = lane&15  (m89-verified layout)
    const int rg = (lane >> 4) * 4;
#pragma unroll
    for (int nf = 0; nf < 4; ++nf) {
        int col = bcol + wc * 64 + nf * 16 + lr;
        float bv = bias[col];
#pragma unroll
        for (int mf = 0; mf < 4; ++mf) {
            int row0 = brow + wr * 64 + mf * 16 + rg;
#pragma unroll
            for (int r = 0; r < 4; ++r) {
                float v = acc[mf][nf][r] + bv;
                if (GELU) v = 0.5f * v * (1.f + erff(v * 0.70710678118654752f));
                C[(size_t)(row0 + r) * N + col] = (TOut)v;
            }
        }
    }
}

extern "C" void kernel_launch(void* const* d_in, const int* in_sizes, int n_in,
                              void* d_out, int out_size, void* d_ws, size_t ws_size,
                              hipStream_t stream) {
    const float* x  = (const float*)d_in[0];
    const float* w1 = (const float*)d_in[1];
    const float* b1 = (const float*)d_in[2];
    const float* w2 = (const float*)d_in[3];
    const float* b2 = (const float*)d_in[4];
    const float* w3 = (const float*)d_in[5];
    const float* b3 = (const float*)d_in[6];

    const int total = (out_size - B_CONST) / H_CONST;  // 32896
    float* out = (float*)d_out;
    float* out_pc = out + (size_t)total * H_CONST;

    char* ws = (char*)d_ws;
    int* valid  = (int*)ws;
    int* pc     = valid + 256;
    int* starts = pc + 256;
    int* cum    = starts + 256;
    __bf16* w1t = (__bf16*)(ws + 4096);                        // 1024x32
    __bf16* w2t = w1t + (size_t)H_CONST * 32;                  // 1024x1024
    __bf16* w3t = w2t + (size_t)H_CONST * H_CONST;             // 1024x1024
    __bf16* patches = w3t + (size_t)H_CONST * H_CONST;         // total x 32
    __bf16* h1 = patches + (size_t)total * 32;                 // total x 1024
    __bf16* h2 = h1 + (size_t)total * H_CONST;                 // total x 1024

    k_valid<<<B_CONST, 256, 0, stream>>>(x, valid);
    k_scan<<<1, B_CONST, 0, stream>>>(valid, pc, starts, cum, out_pc);
    k_gather<<<(total * 32 + 255) / 256, 256, 0, stream>>>(x, valid, cum, starts, patches, total);
    k_w1t<<<4, 256, 0, stream>>>(w1, w1t);
    dim3 tg(H_CONST / 32, H_CONST / 32);
    k_transpose_cvt<<<tg, 256, 0, stream>>>(w2, w2t, H_CONST, H_CONST);
    k_transpose_cvt<<<tg, 256, 0, stream>>>(w3, w3t, H_CONST, H_CONST);

    dim3 blk(256);
    dim3 g(H_CONST / 128, total / 128);   // total = 32896 = 257*128
    k_mfma_gemm<true,  __bf16><<<g, blk, 0, stream>>>(patches, w1t, b1, h1, total, H_CONST, 32);
    k_mfma_gemm<true,  __bf16><<<g, blk, 0, stream>>>(h1, w2t, b2, h2, total, H_CONST, H_CONST);
    k_mfma_gemm<false, float ><<<g, blk, 0, stream>>>(h2, w3t, b3, out, total, H_CONST, H_CONST);
}

// Round 3
// 277.670 us; speedup vs baseline: 9.5461x; 1.1897x over previous
//
#include <hip/hip_runtime.h>
#include <hip/hip_bf16.h>
#include <math.h>

#define B_CONST 256
#define T_CONST 8192
#define P_CONST 16
#define H_CONST 1024

typedef __bf16 bf16x8 __attribute__((ext_vector_type(8)));
typedef __bf16 bf16x4 __attribute__((ext_vector_type(4)));
typedef float  f32x4  __attribute__((ext_vector_type(4)));

typedef __attribute__((address_space(3))) void       as3_void;
typedef const __attribute__((address_space(1))) void as1_cvoid;

__device__ __forceinline__ void gload_lds16(const void* g, void* l) {
    __builtin_amdgcn_global_load_lds((as1_cvoid*)g, (as3_void*)l, 16, 0, 0);
}

// fast gelu: x * sigmoid(1.5957691 * x * (1 + 0.044715 x^2))
// saturates cleanly (exp->inf => rcp->0 => result -0; exp->0 => result x)
__device__ __forceinline__ float gelu_fast(float x) {
    float z = 1.5957691216057308f * x * __builtin_fmaf(0.044715f, x * x, 1.0f);
    return x * __builtin_amdgcn_rcpf(1.0f + __expf(-z));
}

// ---------------- kernel 1: per-batch valid count (sum of mask) ----------------
__global__ void k_valid(const float* __restrict__ x, int* __restrict__ valid) {
    int b = blockIdx.x;
    const float* row = x + (size_t)b * (T_CONST * 2);
    float s = 0.f;
    for (int t = threadIdx.x; t < T_CONST; t += blockDim.x)
        s += row[2 * t + 1];
    __shared__ float red[256];
    red[threadIdx.x] = s;
    __syncthreads();
    for (int off = 128; off > 0; off >>= 1) {
        if (threadIdx.x < off) red[threadIdx.x] += red[threadIdx.x + off];
        __syncthreads();
    }
    if (threadIdx.x == 0) valid[b] = (int)(red[0] + 0.5f);
}

// ---------------- kernel 2: pc + scan; writes pc (as float) to out tail --------
__global__ void k_scan(const int* __restrict__ valid, int* __restrict__ pc,
                       int* __restrict__ starts, int* __restrict__ cum,
                       float* __restrict__ out_pc) {
    __shared__ int s[B_CONST];
    int t = threadIdx.x;
    int v = valid[t];
    int p = (v + P_CONST - 1) / P_CONST;
    s[t] = p;
    __syncthreads();
    for (int off = 1; off < B_CONST; off <<= 1) {
        int add = (t >= off) ? s[t - off] : 0;
        __syncthreads();
        s[t] += add;
        __syncthreads();
    }
    pc[t] = p;
    cum[t] = s[t];
    starts[t] = s[t] - p;
    out_pc[t] = (float)p;
}

// ---------------- kernel 3: gather patches (total x 32 bf16, K padded) ---------
__global__ void k_gather(const float* __restrict__ x, const int* __restrict__ valid,
                         const int* __restrict__ cum, const int* __restrict__ starts,
                         __bf16* __restrict__ patches, int total) {
    int tid = blockIdx.x * blockDim.x + threadIdx.x;
    if (tid >= total * 32) return;
    int j = tid >> 5, k = tid & 31;
    int lo = 0, hi = B_CONST - 1;
    while (lo < hi) { int mid = (lo + hi) >> 1; if (cum[mid] > j) hi = mid; else lo = mid + 1; }
    int b = lo;
    int p = j - starts[b];
    float v = 0.f;
    if (k < 16) {
        int idx = p * P_CONST + k;
        if (idx < valid[b]) v = x[(size_t)b * (T_CONST * 2) + 2 * idx];
    }
    patches[tid] = (__bf16)v;
}

// ---------------- weight prep: transpose K x N fp32 -> N x K bf16 --------------
__global__ void k_transpose_cvt(const float* __restrict__ W, __bf16* __restrict__ WT,
                                int Kdim, int Ndim) {
    __shared__ float tile[32][33];
    int n0 = blockIdx.x * 32, k0 = blockIdx.y * 32;
    int c = threadIdx.x & 31, r0 = threadIdx.x >> 5;
    for (int r = r0; r < 32; r += 8) tile[r][c] = W[(size_t)(k0 + r) * Ndim + n0 + c];
    __syncthreads();
    for (int r = r0; r < 32; r += 8) WT[(size_t)(n0 + r) * Kdim + k0 + c] = (__bf16)tile[c][r];
}

// w1 is 16 x 1024 -> w1t 1024 x 32 (zero-padded K)
__global__ void k_w1t(const float* __restrict__ w1, __bf16* __restrict__ w1t) {
    int n = blockIdx.x * 256 + threadIdx.x;
    if (n >= H_CONST) return;
    for (int k = 0; k < 32; ++k)
        w1t[n * 32 + k] = (k < 16) ? (__bf16)w1[k * H_CONST + n] : (__bf16)0.f;
}

// ---------------- MFMA GEMM: C = act(A @ WT^T + bias) --------------------------
// A: M x K bf16 row-major.  WT: N x K bf16 row-major (i.e. W transposed).
// 128x128 tile, 4 waves (2x2), BK=32, mfma_f32_16x16x32_bf16, m97 structure.
// Operands SWAPPED in the mfma call (computes C^T fragment) so each lane holds
// 4 consecutive COLUMNS of one row -> vectorized bias add + 8B/16B stores.
template <bool GELU, typename TOut>
__global__ __launch_bounds__(256) void k_mfma_gemm(
    const __bf16* __restrict__ A, const __bf16* __restrict__ WT,
    const float* __restrict__ bias, TOut* __restrict__ C,
    int M, int N, int K) {
    __shared__ __bf16 As[128][32];
    __shared__ __bf16 Bs[128][32];

    const int lane = threadIdx.x & 63;
    const int wid  = threadIdx.x >> 6;
    const int wr = wid >> 1, wc = wid & 1;

    // XCD-chunked bijective swizzle (nwg % 8 == 0 for all our grids)
    const int nwg_x = gridDim.x;
    const int orig = blockIdx.y * nwg_x + blockIdx.x;
    const int cpx = (nwg_x * gridDim.y) >> 3;
    const int wgid = (orig & 7) * cpx + (orig >> 3);
    const int brow = (wgid / nwg_x) * 128;
    const int bcol = (wgid % nwg_x) * 128;

    f32x4 acc[4][4];
#pragma unroll
    for (int i = 0; i < 4; ++i)
#pragma unroll
        for (int j = 0; j < 4; ++j)
            acc[i][j] = (f32x4){0.f, 0.f, 0.f, 0.f};

    // staging: each wave issues 2 A-loads + 2 B-loads of 16 rows each.
    const int sr = lane >> 2;         // row within 16-row chunk
    const int sc = (lane & 3) * 8;    // elem offset within 32-elem row
    const size_t a_base = (size_t)(brow + wid * 16 + sr) * K + sc;
    const size_t b_base = (size_t)(bcol + wid * 16 + sr) * K + sc;
    const size_t stride64 = (size_t)64 * K;

    const int lr = lane & 15;
    const int lk = (lane >> 4) * 8;

    for (int kt = 0; kt < K; kt += 32) {
        gload_lds16(A  + a_base + kt,            &As[wid * 16][0]);
        gload_lds16(A  + a_base + stride64 + kt, &As[64 + wid * 16][0]);
        gload_lds16(WT + b_base + kt,            &Bs[wid * 16][0]);
        gload_lds16(WT + b_base + stride64 + kt, &Bs[64 + wid * 16][0]);
        __syncthreads();

        bf16x8 af[4], bfr[4];
#pragma unroll
        for (int mf = 0; mf < 4; ++mf)
            af[mf] = *(const bf16x8*)&As[wr * 64 + mf * 16 + lr][lk];
#pragma unroll
        for (int nf = 0; nf < 4; ++nf)
            bfr[nf] = *(const bf16x8*)&Bs[wc * 64 + nf * 16 + lr][lk];
#pragma unroll
        for (int mf = 0; mf < 4; ++mf)
#pragma unroll
            for (int nf = 0; nf < 4; ++nf)
                acc[mf][nf] = __builtin_amdgcn_mfma_f32_16x16x32_bf16(
                    bfr[nf], af[mf], acc[mf][nf], 0, 0, 0);   // swapped: C^T frag
        __syncthreads();
    }

    // epilogue: C^T frag => row = lane&15, cols = (lane>>4)*4 .. +3 (consecutive)
    const int m_off = lane & 15;
    const int c4 = (lane >> 4) << 2;
#pragma unroll
    for (int nf = 0; nf < 4; ++nf) {
        const int col0 = bcol + wc * 64 + nf * 16 + c4;
        const f32x4 bv = *(const f32x4*)&bias[col0];
#pragma unroll
        for (int mf = 0; mf < 4; ++mf) {
            const int row = brow + wr * 64 + mf * 16 + m_off;
            f32x4 v = acc[mf][nf] + bv;
            if (GELU) {
#pragma unroll
                for (int r = 0; r < 4; ++r) v[r] = gelu_fast(v[r]);
            }
            if constexpr (sizeof(TOut) == 4) {
                *(f32x4*)&C[(size_t)row * N + col0] = v;
            } else {
                bf16x4 o;
#pragma unroll
                for (int r = 0; r < 4; ++r) o[r] = (__bf16)v[r];
                *(bf16x4*)&C[(size_t)row * N + col0] = o;
            }
        }
    }
}

extern "C" void kernel_launch(void* const* d_in, const int* in_sizes, int n_in,
                              void* d_out, int out_size, void* d_ws, size_t ws_size,
                              hipStream_t stream) {
    const float* x  = (const float*)d_in[0];
    const float* w1 = (const float*)d_in[1];
    const float* b1 = (const float*)d_in[2];
    const float* w2 = (const float*)d_in[3];
    const float* b2 = (const float*)d_in[4];
    const float* w3 = (const float*)d_in[5];
    const float* b3 = (const float*)d_in[6];

    const int total = (out_size - B_CONST) / H_CONST;  // 32896
    float* out = (float*)d_out;
    float* out_pc = out + (size_t)total * H_CONST;

    char* ws = (char*)d_ws;
    int* valid  = (int*)ws;
    int* pc     = valid + 256;
    int* starts = pc + 256;
    int* cum    = starts + 256;
    __bf16* w1t = (__bf16*)(ws + 4096);                        // 1024x32
    __bf16* w2t = w1t + (size_t)H_CONST * 32;                  // 1024x1024
    __bf16* w3t = w2t + (size_t)H_CONST * H_CONST;             // 1024x1024
    __bf16* patches = w3t + (size_t)H_CONST * H_CONST;         // total x 32
    __bf16* h1 = patches + (size_t)total * 32;                 // total x 1024
    __bf16* h2 = h1 + (size_t)total * H_CONST;                 // total x 1024

    k_valid<<<B_CONST, 256, 0, stream>>>(x, valid);
    k_scan<<<1, B_CONST, 0, stream>>>(valid, pc, starts, cum, out_pc);
    k_gather<<<(total * 32 + 255) / 256, 256, 0, stream>>>(x, valid, cum, starts, patches, total);
    k_w1t<<<4, 256, 0, stream>>>(w1, w1t);
    dim3 tg(H_CONST / 32, H_CONST / 32);
    k_transpose_cvt<<<tg, 256, 0, stream>>>(w2, w2t, H_CONST, H_CONST);
    k_transpose_cvt<<<tg, 256, 0, stream>>>(w3, w3t, H_CONST, H_CONST);

    dim3 blk(256);
    dim3 g(H_CONST / 128, total / 128);   // 8 x 257 = 2056 blocks, %8 == 0
    k_mfma_gemm<true,  __bf16><<<g, blk, 0, stream>>>(patches, w1t, b1, h1, total, H_CONST, 32);
    k_mfma_gemm<true,  __bf16><<<g, blk, 0, stream>>>(h1, w2t, b2, h2, total, H_CONST, H_CONST);
    k_mfma_gemm<false, float ><<<g, blk, 0, stream>>>(h2, w3t, b3, out, total, H_CONST, H_CONST);
}